// Round 1
// baseline (600.099 us; speedup 1.0000x reference)
//
#include <hip/hip_runtime.h>
#include <math.h>

// DirectBEVProjector: polar warp + bilinear sample.
// feat [B=4, C=256, IH=128, IW=512] f32 -> out [B, C, 128, 512] f32.
// Coordinates depend only on (b,i,j): compute once, loop channels.

#define BEV_H 128
#define BEV_W 512
#define IH 128
#define IW 512
#define C_CH 256
#define B_N 4

__global__ __launch_bounds__(256) void bev_project_kernel(
    const float* __restrict__ feat,
    const float* __restrict__ rot,
    const float* __restrict__ shift_u,
    const float* __restrict__ shift_v,
    const float* __restrict__ mpp,
    float* __restrict__ out)
{
    const float PI_F     = 3.14159265358979323846f;
    const float TWO_PI_F = 6.28318530717958647692f;

    int idx = blockIdx.x * blockDim.x + threadIdx.x;   // 0 .. 262143
    int j = idx & (BEV_W - 1);          // fast-varying: consecutive lanes = consecutive j
    int i = (idx >> 9) & (BEV_H - 1);
    int b = idx >> 16;                  // 512*128 = 65536 per batch

    // ---- coordinate math (mirrors reference exactly, fp32) ----
    float cv = (float)(BEV_H / 2) - 0.5f + shift_v[b];
    float cu = (float)(BEV_W / 2) - 0.5f + shift_u[b];
    float dy = (float)i - cv;
    float dx = (float)j - cu;
    float radius = sqrtf(dy * dy + dx * dx);
    float theta = atan2f(dy, dx);

    float t = fmodf(theta, TWO_PI_F); if (t < 0.0f) t += TWO_PI_F;
    t = -PI_F * 0.5f + t;
    t = fmodf(t, TWO_PI_F); if (t < 0.0f) t += TWO_PI_F;
    t = t + rot[b] * 360.0f / 180.0f * PI_F;           // rot * 2*pi, ref op order
    t = fmodf(t, TWO_PI_F); if (t < 0.0f) t += TWO_PI_F;

    float u = t * (1.0f / TWO_PI_F) * (float)IW;
    float dist = radius * mpp[0];
    float phi = atan2f(dist, -2.0f);                   // GRD_HEIGHT = -2.0
    float v = phi * (1.0f / PI_F) * (float)IH;

    // ---- bilinear corners & weights (clamp-before-weights, faithful) ----
    float ix = u, iy = v;
    float nwx = floorf(ix), nwy = floorf(iy);

    auto cx = [](float x) { return fminf(fmaxf(x, 0.0f), (float)(IW - 1)); };
    auto cy = [](float y) { return fminf(fmaxf(y, 0.0f), (float)(IH - 1)); };

    float ix_ne = cx(nwx + 1.0f), iy_ne = cy(nwy);
    float ix_sw = cx(nwx),        iy_sw = cy(nwy + 1.0f);
    float ix_se = cx(nwx + 1.0f), iy_se = cy(nwy + 1.0f);
    float ix_nw = cx(nwx),        iy_nw = cy(nwy);

    float w_nw = (ix_se - ix) * (iy_se - iy);
    float w_ne = (ix - ix_sw) * (iy_sw - iy);
    float w_sw = (ix_ne - ix) * (iy - iy_ne);
    float w_se = (ix - ix_nw) * (iy - iy_nw);

    int o_nw = (int)iy_nw * IW + (int)ix_nw;
    int o_ne = (int)iy_ne * IW + (int)ix_ne;
    int o_sw = (int)iy_sw * IW + (int)ix_sw;
    int o_se = (int)iy_se * IW + (int)ix_se;

    const float* fb = feat + (size_t)b * C_CH * IH * IW;
    float* ob = out + (size_t)b * C_CH * (BEV_H * BEV_W)
                    + (size_t)i * BEV_W + (size_t)j;

    // ---- channel loop: 4 gathers + fma, coalesced store per channel ----
    #pragma unroll 4
    for (int c = 0; c < C_CH; ++c) {
        const float* p = fb + (size_t)c * (IH * IW);
        float r = w_nw * p[o_nw] + w_ne * p[o_ne]
                + w_sw * p[o_sw] + w_se * p[o_se];
        ob[(size_t)c * (BEV_H * BEV_W)] = r;
    }
}

extern "C" void kernel_launch(void* const* d_in, const int* in_sizes, int n_in,
                              void* d_out, int out_size, void* d_ws, size_t ws_size,
                              hipStream_t stream) {
    const float* feat    = (const float*)d_in[0];
    const float* rot     = (const float*)d_in[1];
    const float* shift_u = (const float*)d_in[2];
    const float* shift_v = (const float*)d_in[3];
    const float* mpp     = (const float*)d_in[4];
    float* out = (float*)d_out;

    const int total = B_N * BEV_H * BEV_W;   // 262144 threads
    dim3 block(256);
    dim3 grid(total / 256);                  // 1024 blocks
    bev_project_kernel<<<grid, block, 0, stream>>>(feat, rot, shift_u, shift_v, mpp, out);
}

// Round 2
// 490.504 us; speedup vs baseline: 1.2234x; 1.2234x over previous
//
#include <hip/hip_runtime.h>
#include <math.h>

// DirectBEVProjector: polar warp + bilinear sample.
// feat [B=4, C=256, IH=128, IW=512] f32 -> out [B, C, 128, 512] f32.
// R1: channel-split 8x (CPT=32) for TLP — was latency-bound at 21% HBM BW
// with only 16 waves/CU. Coord math redundantly recomputed per group (cheap:
// inner gather loop dominates VALU). Nontemporal stores for streaming output.

#define BEV_H 128
#define BEV_W 512
#define IH 128
#define IW 512
#define C_CH 256
#define B_N 4
#define CPT 32                       // channels per thread
#define GROUPS (C_CH / CPT)          // 8 channel groups

__global__ __launch_bounds__(256) void bev_project_kernel(
    const float* __restrict__ feat,
    const float* __restrict__ rot,
    const float* __restrict__ shift_u,
    const float* __restrict__ shift_v,
    const float* __restrict__ mpp,
    float* __restrict__ out)
{
    const float PI_F     = 3.14159265358979323846f;
    const float TWO_PI_F = 6.28318530717958647692f;

    int idx = blockIdx.x * blockDim.x + threadIdx.x;  // 0 .. 2M-1
    int j  = idx & (BEV_W - 1);         // lanes consecutive in j -> coalesced store
    int i  = (idx >> 9) & (BEV_H - 1);
    int b  = (idx >> 16) & (B_N - 1);
    int cg = idx >> 18;                 // channel group, slowest

    // ---- coordinate math (mirrors reference exactly, fp32) ----
    float cv = (float)(BEV_H / 2) - 0.5f + shift_v[b];
    float cu = (float)(BEV_W / 2) - 0.5f + shift_u[b];
    float dy = (float)i - cv;
    float dx = (float)j - cu;
    float radius = sqrtf(dy * dy + dx * dx);
    float theta = atan2f(dy, dx);

    float t = fmodf(theta, TWO_PI_F); if (t < 0.0f) t += TWO_PI_F;
    t = -PI_F * 0.5f + t;
    t = fmodf(t, TWO_PI_F); if (t < 0.0f) t += TWO_PI_F;
    t = t + rot[b] * 360.0f / 180.0f * PI_F;          // rot * 2*pi, ref op order
    t = fmodf(t, TWO_PI_F); if (t < 0.0f) t += TWO_PI_F;

    float u = t * (1.0f / TWO_PI_F) * (float)IW;
    float dist = radius * mpp[0];
    float phi = atan2f(dist, -2.0f);                  // GRD_HEIGHT = -2.0
    float v = phi * (1.0f / PI_F) * (float)IH;

    // ---- bilinear corners & weights (clamp-before-weights, faithful) ----
    float ix = u, iy = v;
    float nwx = floorf(ix), nwy = floorf(iy);

    auto cx = [](float x) { return fminf(fmaxf(x, 0.0f), (float)(IW - 1)); };
    auto cy = [](float y) { return fminf(fmaxf(y, 0.0f), (float)(IH - 1)); };

    float ix_ne = cx(nwx + 1.0f), iy_ne = cy(nwy);
    float ix_sw = cx(nwx),        iy_sw = cy(nwy + 1.0f);
    float ix_se = cx(nwx + 1.0f), iy_se = cy(nwy + 1.0f);
    float ix_nw = cx(nwx),        iy_nw = cy(nwy);

    float w_nw = (ix_se - ix) * (iy_se - iy);
    float w_ne = (ix - ix_sw) * (iy_sw - iy);
    float w_sw = (ix_ne - ix) * (iy - iy_ne);
    float w_se = (ix - ix_nw) * (iy - iy_nw);

    int o_nw = (int)iy_nw * IW + (int)ix_nw;
    int o_ne = (int)iy_ne * IW + (int)ix_ne;
    int o_sw = (int)iy_sw * IW + (int)ix_sw;
    int o_se = (int)iy_se * IW + (int)ix_se;

    const int c0 = cg * CPT;
    const float* fb = feat + ((size_t)b * C_CH + c0) * (IH * IW);
    float* ob = out + ((size_t)b * C_CH + c0) * (BEV_H * BEV_W)
                    + (size_t)i * BEV_W + (size_t)j;

    // ---- channel loop: 4 gathers + fma, coalesced nontemporal store ----
    #pragma unroll 4
    for (int c = 0; c < CPT; ++c) {
        const float* p = fb + (size_t)c * (IH * IW);
        float r = w_nw * p[o_nw] + w_ne * p[o_ne]
                + w_sw * p[o_sw] + w_se * p[o_se];
        __builtin_nontemporal_store(r, &ob[(size_t)c * (BEV_H * BEV_W)]);
    }
}

extern "C" void kernel_launch(void* const* d_in, const int* in_sizes, int n_in,
                              void* d_out, int out_size, void* d_ws, size_t ws_size,
                              hipStream_t stream) {
    const float* feat    = (const float*)d_in[0];
    const float* rot     = (const float*)d_in[1];
    const float* shift_u = (const float*)d_in[2];
    const float* shift_v = (const float*)d_in[3];
    const float* mpp     = (const float*)d_in[4];
    float* out = (float*)d_out;

    const int total = B_N * BEV_H * BEV_W * GROUPS;  // 2,097,152 threads
    dim3 block(256);
    dim3 grid(total / 256);                          // 8192 blocks
    bev_project_kernel<<<grid, block, 0, stream>>>(feat, rot, shift_u, shift_v, mpp, out);
}